// Round 10
// baseline (120.840 us; speedup 1.0000x reference)
//
#include <hip/hip_runtime.h>
#include <math.h>

// Problem constants
#define BB 64      // batches
#define NN 256     // sequence length
#define DD 64      // feature dim
#define TT 4096    // task pool size

// Tiling
#define NCH 8                  // t-chunks (blocks per batch)
#define CT (TT/NCH)            // 512 tasks per block
#define THREADS 512
#define WAVES 8                // each wave owns 64 tasks (4 MFMA row-tiles)
#define NTILE 4                // 16-task row-tiles per wave
#define NB 32                  // n rows per staged group (2 halves of 16)
#define NGRP (NN/NB)           // 8
#define BN (BB*NN)             // 16384 outputs

#define NHL2E (-0.72134752044448170368f)     // -0.5 * log2(e)

typedef __bf16 bf16x4 __attribute__((ext_vector_type(4)));
typedef __bf16 bf16x8 __attribute__((ext_vector_type(8)));
typedef float  f32x4  __attribute__((ext_vector_type(4)));

// DPP row_shr ctrl codes
#define SHR1 0x111
#define SHR2 0x112
#define SHR4 0x114
#define SHR8 0x118

template<int C>
__device__ __forceinline__ float dppf(float x) {
  return __int_as_float(__builtin_amdgcn_update_dpp(
      0, __float_as_int(x), C, 0xf, 0xf, true));
}

// broadcast lane15 of each 16-lane group (BitMode: and=0x10, or=0xF)
__device__ __forceinline__ float bcast15(float x) {
  return __int_as_float(__builtin_amdgcn_ds_swizzle(__float_as_int(x), 0x1F0));
}

#define GLOAD_LDS16(gp, lp_) \
  __builtin_amdgcn_global_load_lds((const __attribute__((address_space(1))) void*)(gp), \
                                   (__attribute__((address_space(3))) void*)(lp_), 16, 0, 0)

// Merge the 8 wave-partials (packed L = m + log2 s, R = v/s) of one group
// (32 n-cols). PLAIN stores: the kernel boundary before phase2 provides
// cross-XCD coherence (round-5-proven; agent-scope relaxed atomics did NOT).
__device__ __forceinline__ void merge32(const float2 (*sb)[NB], int lane,
                                        float2* __restrict__ part, size_t obase) {
  const int col = lane & 31;
  float2 p0 = sb[0][col];
  float M = p0.x, S = 1.f, V = p0.y;
  #pragma unroll
  for (int w = 1; w < WAVES; ++w) {
    float2 pw = sb[w][col];
    float mn = fmaxf(M, pw.x);
    float ea = __builtin_amdgcn_exp2f(M - mn);
    float eb = __builtin_amdgcn_exp2f(pw.x - mn);
    S = S * ea + eb;
    V = fmaf(V, ea, pw.y * eb);
    M = mn;
  }
  if (lane < 32) {
    float2 lr;
    lr.x = M + __log2f(S);
    lr.y = V / S;
    part[obase + (size_t)col * NCH] = lr;
  }
}

// ---------------------------------------------------------------------------
// Kernel 1: block = (batch b, chunk of 512 tasks). Each wave owns 64 tasks
// (4 row-tiles); 8 groups of 32 n-rows, each group = two 16-n halves sharing
// W fragments. vs round 9 (NCH=16): half the blocks -> total W-prep, merge,
// staging and barrier costs halve; 4 ds_read_b128 feed 24 MFMAs (2x LDS
// amortization). Per-half EXACT softmax max is kept deliberately: z~N(0,64)
// makes deferred-max underflow sv to 0 (NaN) -- verified by arithmetic.
__global__ __launch_bounds__(THREADS, 3)
void mmse_phase1(const float* __restrict__ data,
                 const float* __restrict__ targets,
                 const float* __restrict__ Wp,     // (T, D) row-major
                 float2* __restrict__ part)        // (BN, NCH) packed (L,R)
{
  const int bx   = blockIdx.x;
  const int b    = bx >> 3;
  const int ch   = bx & 7;
  const int tid  = threadIdx.x;
  const int lane = tid & 63;
  const int wave = tid >> 6;

  __shared__ uint4  dbufq[2][512];          // 2 x 8 KB swizzled tile images
  __shared__ float  tgl[NN];                // targets for this batch
  __shared__ float2 sbuf[2][WAVES][NB];     // wave partials (L, R)

  unsigned char* dbufc = (unsigned char*)dbufq;

  // ---- W fragments -> registers (hi/lo). A-layout: row=l&15, k=(l>>4)*8+j
  bf16x8 aH[NTILE][2], aL[NTILE][2];
  {
    const int tb = ch * CT + wave * 64;
    #pragma unroll
    for (int tile = 0; tile < NTILE; ++tile) {
      #pragma unroll
      for (int s = 0; s < 2; ++s) {
        const int row = tb + tile * 16 + (lane & 15);
        const int kb  = s * 32 + (lane >> 4) * 8;
        const float* wp = Wp + (size_t)row * DD + kb;
        const float4 qa = *(const float4*)wp;
        const float4 qb = *(const float4*)(wp + 4);
        float f[8] = {qa.x, qa.y, qa.z, qa.w, qb.x, qb.y, qb.z, qb.w};
        bf16x8 hv, lv;
        #pragma unroll
        for (int j = 0; j < 8; ++j) {
          const __bf16 hj = (__bf16)f[j];
          hv[j] = hj;
          lv[j] = (__bf16)(f[j] - (float)hj);
        }
        aH[tile][s] = hv; aL[tile][s] = lv;
      }
    }
  }

  // stage targets (1 KB) via async global->LDS
  if (wave == 0)
    GLOAD_LDS16(targets + (size_t)b * NN + lane * 4, tgl);

  const float* __restrict__ dbase = data + (size_t)b * NN * DD;
  // staging coords: thread -> (n row sn of 32, 4-float k-slot sk8)
  const int sn  = tid >> 4;          // 0..31
  const int sk8 = tid & 15;          // 0..15
  const int sphys = (sn * 128 + sk8 * 8) ^ ((sn & 7) << 4);   // 8B-aligned

  // stage group 0 (load + convert + swizzled write)
  {
    const float4 q = *(const float4*)(dbase + (size_t)sn * DD + sk8 * 4);
    float f[4] = {q.x, q.y, q.z, q.w};
    bf16x4 hv, lv;
    #pragma unroll
    for (int j = 0; j < 4; ++j) {
      const __bf16 hj = (__bf16)f[j];
      hv[j] = hj;
      lv[j] = (__bf16)(f[j] - (float)hj);
    }
    *(bf16x4*)(dbufc + sphys)        = hv;
    *(bf16x4*)(dbufc + 4096 + sphys) = lv;
  }
  __syncthreads();

  float c16[16];
  #pragma unroll
  for (int i = 0; i < 16; ++i) c16[i] = 0.f;

  const size_t obase0 = (size_t)(b * NN) * NCH + ch;
  // Swizzled fragment base; second k-step is ra^64 (NOT ra+64: the add
  // carries into row bits when (lane&4) != 0).
  const int ra = ((lane & 15) * 128 + (lane >> 4) * 16) ^ ((lane & 7) << 4);

  #pragma unroll 1
  for (int g = 0; g < NGRP; ++g) {
    const int buf = g & 1;
    const unsigned char* bp = dbufc + buf * 8192;

    // issue next group's global load early (hides HBM/L2 latency under MFMA)
    float4 q;
    if (g + 1 < NGRP)
      q = *(const float4*)(dbase + (size_t)((g + 1) * NB + sn) * DD + sk8 * 4);

    // merge previous group's wave partials (round-robin wave)
    if (g > 0 && wave == ((g - 1) & 7))
      merge32(sbuf[(g - 1) & 1], lane, part, obase0 + (size_t)((g - 1) * NB) * NCH);

    #pragma unroll
    for (int h = 0; h < 2; ++h) {
      const unsigned char* hp = bp + h * 2048;
      bf16x8 bh0 = *(const bf16x8*)(hp + ra);
      bf16x8 bh1 = *(const bf16x8*)(hp + (ra ^ 64));
      bf16x8 bl0 = *(const bf16x8*)(hp + 4096 + ra);
      bf16x8 bl1 = *(const bf16x8*)(hp + 4096 + (ra ^ 64));

      // bf16x3 MFMA: z = wH*dH + wH*dL + wL*dH  (24 MFMAs per 4 LDS reads)
      f32x4 zz[NTILE];
      __builtin_amdgcn_s_setprio(1);
      #pragma unroll
      for (int t = 0; t < NTILE; ++t) {
        zz[t] = (f32x4)(0.f);
        zz[t] = __builtin_amdgcn_mfma_f32_16x16x32_bf16(aH[t][0], bh0, zz[t], 0, 0, 0);
        zz[t] = __builtin_amdgcn_mfma_f32_16x16x32_bf16(aH[t][0], bl0, zz[t], 0, 0, 0);
        zz[t] = __builtin_amdgcn_mfma_f32_16x16x32_bf16(aL[t][0], bh0, zz[t], 0, 0, 0);
        zz[t] = __builtin_amdgcn_mfma_f32_16x16x32_bf16(aH[t][1], bh1, zz[t], 0, 0, 0);
        zz[t] = __builtin_amdgcn_mfma_f32_16x16x32_bf16(aH[t][1], bl1, zz[t], 0, 0, 0);
        zz[t] = __builtin_amdgcn_mfma_f32_16x16x32_bf16(aL[t][1], bh1, zz[t], 0, 0, 0);
      }
      __builtin_amdgcn_s_setprio(0);

      const float tgf = tgl[g * NB + h * 16 + (lane & 15)];

      // ---- scan + softmax (log2 space, EXACT per-half max) ----
      float alpha[16];
      float mloc = -3.4e38f;
      #pragma unroll
      for (int t = 0; t < NTILE; ++t) {
        #pragma unroll
        for (int r = 0; r < 4; ++r) {
          const int t16 = t * 4 + r;
          const float z  = zz[t][r];
          const float rr = tgf - z;
          const float lp = rr * rr * NHL2E;
          float x = lp;
          x += dppf<SHR1>(x);
          x += dppf<SHR2>(x);
          x += dppf<SHR4>(x);
          x += dppf<SHR8>(x);                  // inclusive prefix over 16 cols
          const float tot = bcast15(x);        // group total (LDS pipe)
          const float a_ = c16[t16] + (x - lp); // carry + exclusive prefix
          alpha[t16] = a_;
          c16[t16] += tot;
          mloc = fmaxf(mloc, a_);
        }
      }
      float m = fmaxf(mloc, __shfl_xor(mloc, 16));
      m = fmaxf(m, __shfl_xor(m, 32));
      float sv = 0.f, vv = 0.f;
      #pragma unroll
      for (int t = 0; t < NTILE; ++t) {
        #pragma unroll
        for (int r = 0; r < 4; ++r) {
          const float p = __builtin_amdgcn_exp2f(alpha[t * 4 + r] - m);
          sv += p;
          vv = fmaf(p, zz[t][r], vv);
        }
      }
      sv += __shfl_xor(sv, 16); sv += __shfl_xor(sv, 32);
      vv += __shfl_xor(vv, 16); vv += __shfl_xor(vv, 32);
      if (lane < 16) {
        float2 lr;
        lr.x = m + __log2f(sv);
        lr.y = vv / sv;
        sbuf[buf][wave][h * 16 + lane] = lr;
      }
    }

    // convert + swizzled write of next group into the other buffer
    if (g + 1 < NGRP) {
      float f[4] = {q.x, q.y, q.z, q.w};
      bf16x4 hv, lv;
      #pragma unroll
      for (int j = 0; j < 4; ++j) {
        const __bf16 hj = (__bf16)f[j];
        hv[j] = hj;
        lv[j] = (__bf16)(f[j] - (float)hj);
      }
      unsigned char* wb = dbufc + (buf ^ 1) * 8192;
      *(bf16x4*)(wb + sphys)        = hv;
      *(bf16x4*)(wb + 4096 + sphys) = lv;
    }
    __syncthreads();
  }

  if (wave == ((NGRP - 1) & 7))
    merge32(sbuf[(NGRP - 1) & 1], lane, part, obase0 + (size_t)((NGRP - 1) * NB) * NCH);
}

// ---------------------------------------------------------------------------
// Kernel 2: merge the NCH=8 chunk partials per output. 1 thread per output,
// 8 contiguous (L,R) pairs (64 B). Each (L,R) partial == (m=L, s=1, v=R).
__global__ __launch_bounds__(256)
void mmse_phase2(const float2* __restrict__ part, float* __restrict__ out)
{
  const int idx = blockIdx.x * 256 + threadIdx.x;   // = b*NN + n
  const float2* __restrict__ p = part + (size_t)idx * NCH;
  float2 q0 = p[0];
  float M = q0.x, S = 1.f, V = q0.y;
  #pragma unroll
  for (int c = 1; c < NCH; ++c) {
    const float2 q = p[c];
    const float mn = fmaxf(M, q.x);
    const float ea = __builtin_amdgcn_exp2f(M - mn);
    const float eb = __builtin_amdgcn_exp2f(q.x - mn);
    S = fmaf(S, ea, eb);
    V = fmaf(V, ea, q.y * eb);
    M = mn;
  }
  out[idx] = V / S;
}

extern "C" void kernel_launch(void* const* d_in, const int* in_sizes, int n_in,
                              void* d_out, int out_size, void* d_ws, size_t ws_size,
                              hipStream_t stream)
{
  const float* data      = (const float*)d_in[0];   // (64,256,64)
  const float* targets   = (const float*)d_in[1];   // (64,256)
  const float* task_pool = (const float*)d_in[2];   // (4096,64,1) == (T,D)
  float* out = (float*)d_out;                       // (64,256)

  float2* part = (float2*)d_ws;                     // BN*NCH*8 = 1 MB

  hipLaunchKernelGGL(mmse_phase1, dim3(BB * NCH), dim3(THREADS), 0, stream,
                     data, targets, task_pool, part);
  hipLaunchKernelGGL(mmse_phase2, dim3(BN / 256), dim3(256), 0, stream,
                     part, out);
}

// Round 12
// 110.689 us; speedup vs baseline: 1.0917x; 1.0917x over previous
//
#include <hip/hip_runtime.h>
#include <math.h>

// Problem constants
#define BB 64      // batches
#define NN 256     // sequence length
#define DD 64      // feature dim
#define TT 4096    // task pool size

// Tiling  (>=1024 blocks is load-bearing: R10 showed NCH=8 regresses)
#define NCH 16                 // t-chunks (blocks per batch)
#define CT (TT/NCH)            // 256 tasks per block
#define THREADS 512
#define WAVES 8                // each wave owns 32 tasks (2 MFMA row-tiles)
#define NB 32                  // n rows per staged group (2 halves of 16)
#define NGRP (NN/NB)           // 8
#define BN (BB*NN)             // 16384 outputs

#define NHL2E (-0.72134752044448170368f)     // -0.5 * log2(e)

typedef __bf16 bf16x4 __attribute__((ext_vector_type(4)));
typedef __bf16 bf16x8 __attribute__((ext_vector_type(8)));
typedef float  f32x4  __attribute__((ext_vector_type(4)));

// DPP row_shr ctrl codes
#define SHR1 0x111
#define SHR2 0x112
#define SHR4 0x114
#define SHR8 0x118

template<int C>
__device__ __forceinline__ float dppf(float x) {
  return __int_as_float(__builtin_amdgcn_update_dpp(
      0, __float_as_int(x), C, 0xf, 0xf, true));
}

// broadcast lane15 of each 16-lane group (BitMode: and=0x10, or=0xF)
__device__ __forceinline__ float bcast15(float x) {
  return __int_as_float(__builtin_amdgcn_ds_swizzle(__float_as_int(x), 0x1F0));
}

#define GLOAD_LDS16(gp, lp_) \
  __builtin_amdgcn_global_load_lds((const __attribute__((address_space(1))) void*)(gp), \
                                   (__attribute__((address_space(3))) void*)(lp_), 16, 0, 0)

// Merge the 8 wave-partials (raw m, s, v) of one group (32 n-cols); emit
// packed (L = m + log2 s, R = v/s). PLAIN stores: the kernel boundary before
// phase2 provides cross-XCD coherence (round-5-proven; agent-scope relaxed
// atomics demonstrably did NOT -- round 7).
__device__ __forceinline__ void merge32(const float4 (*sb)[NB], int lane,
                                        float2* __restrict__ part, size_t obase) {
  const int col = lane & 31;
  float4 p0 = sb[0][col];
  float M = p0.x, S = p0.y, V = p0.z;
  #pragma unroll
  for (int w = 1; w < WAVES; ++w) {
    float4 pw = sb[w][col];
    float mn = fmaxf(M, pw.x);
    float ea = __builtin_amdgcn_exp2f(M - mn);
    float eb = __builtin_amdgcn_exp2f(pw.x - mn);
    S = fmaf(S, ea, pw.y * eb);
    V = fmaf(V, ea, pw.z * eb);
    M = mn;
  }
  if (lane < 32) {
    float2 lr;
    lr.x = M + __log2f(S);
    lr.y = V / S;
    part[obase + (size_t)col * NCH] = lr;
  }
}

// ---------------------------------------------------------------------------
// Kernel 1: block = (batch b, chunk of 256 tasks), XCD-swizzled so all 16
// chunk-blocks of a batch share one XCD's L2 (data/targets reuse axis).
// 8 groups of 32 n-rows, two 16-n halves per group sharing W fragments.
//  - data f32 -> bf16 hi/lo split (native casts), XOR-swizzled LDS image;
//    float4 global load issued one group ahead (T14).
//  - tasks on MFMA C-rows, n on C-cols; log2-space logp; DPP inclusive scan
//    + ds_swizzle lane15 broadcast for the carry.
//  - softmax max is the EXACT PER-COLUMN max (mloc over the lane's 8 tasks,
//    then shfl_xor(16/32) which combines same-column lanes). A carry-based
//    upper bound shared across columns underflows sv to 0 at late columns
//    (gap ~0.72*sum(r^2) ~ 500+ log2 units) -> 0/0 NaN. R11 proved this.
//  - per-wave raw (m,s,v) partials merged across 8 waves in LDS (round-robin
//    merge wave); chunk partials (L,R) plain-stored; phase2 merges chunks.
__global__ __launch_bounds__(THREADS, 4)
void mmse_phase1(const float* __restrict__ data,
                 const float* __restrict__ targets,
                 const float* __restrict__ Wp,     // (T, D) row-major
                 float2* __restrict__ part)        // (BN, NCH) packed (L,R)
{
  const int bx   = blockIdx.x;
  // XCD-batch swizzle: batch -> fixed XCD residue; bijective over 1024.
  const int b    = ((bx >> 7) << 3) | (bx & 7);
  const int ch   = (bx >> 3) & 15;
  const int tid  = threadIdx.x;
  const int lane = tid & 63;
  const int wave = tid >> 6;

  __shared__ uint4  dbufq[2][512];          // 2 x 8 KB swizzled tile images
  __shared__ float  tgl[NN];                // targets for this batch
  __shared__ float4 sbuf[2][WAVES][NB];     // wave partials (m, s, v, -)

  unsigned char* dbufc = (unsigned char*)dbufq;

  // ---- W fragments -> registers (hi/lo). A-layout: row=l&15, k=(l>>4)*8+j
  bf16x8 aH[2][2], aL[2][2];
  {
    const int tb = ch * CT + wave * 32;
    #pragma unroll
    for (int tile = 0; tile < 2; ++tile) {
      #pragma unroll
      for (int s = 0; s < 2; ++s) {
        const int row = tb + tile * 16 + (lane & 15);
        const int kb  = s * 32 + (lane >> 4) * 8;
        const float* wp = Wp + (size_t)row * DD + kb;
        const float4 qa = *(const float4*)wp;
        const float4 qb = *(const float4*)(wp + 4);
        float f[8] = {qa.x, qa.y, qa.z, qa.w, qb.x, qb.y, qb.z, qb.w};
        bf16x8 hv, lv;
        #pragma unroll
        for (int j = 0; j < 8; ++j) {
          const __bf16 hj = (__bf16)f[j];
          hv[j] = hj;
          lv[j] = (__bf16)(f[j] - (float)hj);
        }
        aH[tile][s] = hv; aL[tile][s] = lv;
      }
    }
  }

  // stage targets (1 KB) via async global->LDS
  if (wave == 0)
    GLOAD_LDS16(targets + (size_t)b * NN + lane * 4, tgl);

  const float* __restrict__ dbase = data + (size_t)b * NN * DD;
  // staging coords: thread -> (n row sn of 32, 4-float k-slot sk8)
  const int sn  = tid >> 4;          // 0..31
  const int sk8 = tid & 15;          // 0..15
  const int sphys = (sn * 128 + sk8 * 8) ^ ((sn & 7) << 4);   // 8B-aligned

  // stage group 0 (load + convert + swizzled write)
  {
    const float4 q = *(const float4*)(dbase + (size_t)sn * DD + sk8 * 4);
    float f[4] = {q.x, q.y, q.z, q.w};
    bf16x4 hv, lv;
    #pragma unroll
    for (int j = 0; j < 4; ++j) {
      const __bf16 hj = (__bf16)f[j];
      hv[j] = hj;
      lv[j] = (__bf16)(f[j] - (float)hj);
    }
    *(bf16x4*)(dbufc + sphys)        = hv;
    *(bf16x4*)(dbufc + 4096 + sphys) = lv;
  }
  __syncthreads();

  float c8[8];
  #pragma unroll
  for (int i = 0; i < 8; ++i) c8[i] = 0.f;

  const size_t obase0 = (size_t)(b * NN) * NCH + ch;
  // Swizzled fragment base; second k-step is ra^64 (NOT ra+64: the add
  // carries into row bits when (lane&4) != 0).
  const int ra = ((lane & 15) * 128 + (lane >> 4) * 16) ^ ((lane & 7) << 4);

  #pragma unroll 1
  for (int g = 0; g < NGRP; ++g) {
    const int buf = g & 1;
    const unsigned char* bp = dbufc + buf * 8192;

    // issue next group's global load early (hides HBM/L2 latency under MFMA)
    float4 q;
    if (g + 1 < NGRP)
      q = *(const float4*)(dbase + (size_t)((g + 1) * NB + sn) * DD + sk8 * 4);

    // merge previous group's wave partials (round-robin wave)
    if (g > 0 && wave == ((g - 1) & 7))
      merge32(sbuf[(g - 1) & 1], lane, part, obase0 + (size_t)((g - 1) * NB) * NCH);

    #pragma unroll
    for (int h = 0; h < 2; ++h) {
      const unsigned char* hp = bp + h * 2048;
      bf16x8 bh0 = *(const bf16x8*)(hp + ra);
      bf16x8 bh1 = *(const bf16x8*)(hp + (ra ^ 64));
      bf16x8 bl0 = *(const bf16x8*)(hp + 4096 + ra);
      bf16x8 bl1 = *(const bf16x8*)(hp + 4096 + (ra ^ 64));

      // bf16x3 MFMA: z = wH*dH + wH*dL + wL*dH
      f32x4 zz[2];
      zz[0] = (f32x4)(0.f); zz[1] = (f32x4)(0.f);
      __builtin_amdgcn_s_setprio(1);
      zz[0] = __builtin_amdgcn_mfma_f32_16x16x32_bf16(aH[0][0], bh0, zz[0], 0, 0, 0);
      zz[0] = __builtin_amdgcn_mfma_f32_16x16x32_bf16(aH[0][0], bl0, zz[0], 0, 0, 0);
      zz[0] = __builtin_amdgcn_mfma_f32_16x16x32_bf16(aL[0][0], bh0, zz[0], 0, 0, 0);
      zz[0] = __builtin_amdgcn_mfma_f32_16x16x32_bf16(aH[0][1], bh1, zz[0], 0, 0, 0);
      zz[0] = __builtin_amdgcn_mfma_f32_16x16x32_bf16(aH[0][1], bl1, zz[0], 0, 0, 0);
      zz[0] = __builtin_amdgcn_mfma_f32_16x16x32_bf16(aL[0][1], bh1, zz[0], 0, 0, 0);
      zz[1] = __builtin_amdgcn_mfma_f32_16x16x32_bf16(aH[1][0], bh0, zz[1], 0, 0, 0);
      zz[1] = __builtin_amdgcn_mfma_f32_16x16x32_bf16(aH[1][0], bl0, zz[1], 0, 0, 0);
      zz[1] = __builtin_amdgcn_mfma_f32_16x16x32_bf16(aL[1][0], bh0, zz[1], 0, 0, 0);
      zz[1] = __builtin_amdgcn_mfma_f32_16x16x32_bf16(aH[1][1], bh1, zz[1], 0, 0, 0);
      zz[1] = __builtin_amdgcn_mfma_f32_16x16x32_bf16(aH[1][1], bl1, zz[1], 0, 0, 0);
      zz[1] = __builtin_amdgcn_mfma_f32_16x16x32_bf16(aL[1][1], bh1, zz[1], 0, 0, 0);
      __builtin_amdgcn_s_setprio(0);

      const float tgf = tgl[g * NB + h * 16 + (lane & 15)];

      // ---- scan + softmax (log2 space, EXACT per-column max) ----
      float alpha[8];
      float mloc = -3.4e38f;
      #pragma unroll
      for (int tile = 0; tile < 2; ++tile) {
        #pragma unroll
        for (int r = 0; r < 4; ++r) {
          const int t8 = tile * 4 + r;
          const float z  = zz[tile][r];
          const float rr = tgf - z;
          const float lp = rr * rr * NHL2E;
          float x = lp;
          x += dppf<SHR1>(x);
          x += dppf<SHR2>(x);
          x += dppf<SHR4>(x);
          x += dppf<SHR8>(x);                 // inclusive prefix over 16 cols
          const float tot = bcast15(x);       // group total (LDS pipe)
          const float a_ = c8[t8] + (x - lp); // carry + exclusive prefix
          alpha[t8] = a_;
          c8[t8] += tot;
          mloc = fmaxf(mloc, a_);
        }
      }
      // per-column max over the wave's 32 tasks (lanes l, l^16, l^32, l^48
      // share the same n-column l&15)
      float m = fmaxf(mloc, __shfl_xor(mloc, 16));
      m = fmaxf(m, __shfl_xor(m, 32));
      float sv = 0.f, vv = 0.f;
      #pragma unroll
      for (int tile = 0; tile < 2; ++tile) {
        #pragma unroll
        for (int r = 0; r < 4; ++r) {
          const float p = __builtin_amdgcn_exp2f(alpha[tile * 4 + r] - m);
          sv += p;
          vv = fmaf(p, zz[tile][r], vv);
        }
      }
      sv += __shfl_xor(sv, 16); sv += __shfl_xor(sv, 32);
      vv += __shfl_xor(vv, 16); vv += __shfl_xor(vv, 32);
      if (lane < 16)
        sbuf[buf][wave][h * 16 + lane] = make_float4(m, sv, vv, 0.f);
    }

    // convert + swizzled write of next group into the other buffer
    if (g + 1 < NGRP) {
      float f[4] = {q.x, q.y, q.z, q.w};
      bf16x4 hv, lv;
      #pragma unroll
      for (int j = 0; j < 4; ++j) {
        const __bf16 hj = (__bf16)f[j];
        hv[j] = hj;
        lv[j] = (__bf16)(f[j] - (float)hj);
      }
      unsigned char* wb = dbufc + (buf ^ 1) * 8192;
      *(bf16x4*)(wb + sphys)        = hv;
      *(bf16x4*)(wb + 4096 + sphys) = lv;
    }
    __syncthreads();
  }

  if (wave == ((NGRP - 1) & 7))
    merge32(sbuf[(NGRP - 1) & 1], lane, part, obase0 + (size_t)((NGRP - 1) * NB) * NCH);
}

// ---------------------------------------------------------------------------
// Kernel 2: merge the NCH=16 chunk partials per output. 2 threads per output,
// 8 contiguous (L,R) pairs each (64 B), pair-merged via shfl_xor(1).
// Each (L,R) partial == (m=L, s=1, v=R).
__global__ __launch_bounds__(256)
void mmse_phase2(const float* __restrict__ part, float* __restrict__ out)
{
  const int gid  = blockIdx.x * 256 + threadIdx.x;
  const int idx  = gid >> 1;          // = b*NN + n
  const int half = gid & 1;
  const float2* __restrict__ p = (const float2*)part + (size_t)idx * NCH + half * 8;
  float M = -3.4e38f, S = 0.f, V = 0.f;
  #pragma unroll
  for (int c = 0; c < 8; ++c) {
    const float2 q = p[c];
    const float mn = fmaxf(M, q.x);
    const float ea = __builtin_amdgcn_exp2f(M - mn);
    const float eb = __builtin_amdgcn_exp2f(q.x - mn);
    S = fmaf(S, ea, eb);
    V = fmaf(V, ea, q.y * eb);
    M = mn;
  }
  const float m2 = __shfl_xor(M, 1), s2 = __shfl_xor(S, 1), v2 = __shfl_xor(V, 1);
  const float mn = fmaxf(M, m2);
  const float ea = __builtin_amdgcn_exp2f(M - mn);
  const float eb = __builtin_amdgcn_exp2f(m2 - mn);
  S = fmaf(S, ea, s2 * eb);
  V = fmaf(V, ea, v2 * eb);
  if (half == 0) out[idx] = V / S;
}

extern "C" void kernel_launch(void* const* d_in, const int* in_sizes, int n_in,
                              void* d_out, int out_size, void* d_ws, size_t ws_size,
                              hipStream_t stream)
{
  const float* data      = (const float*)d_in[0];   // (64,256,64)
  const float* targets   = (const float*)d_in[1];   // (64,256)
  const float* task_pool = (const float*)d_in[2];   // (4096,64,1) == (T,D)
  float* out = (float*)d_out;                       // (64,256)

  float2* part = (float2*)d_ws;                     // BN*NCH*8 = 2 MB

  hipLaunchKernelGGL(mmse_phase1, dim3(BB * NCH), dim3(THREADS), 0, stream,
                     data, targets, task_pool, part);
  hipLaunchKernelGGL(mmse_phase2, dim3(2 * BN / 256), dim3(256), 0, stream,
                     (const float*)part, out);
}